// Round 6
// baseline (4643.785 us; speedup 1.0000x reference)
//
#include <hip/hip_runtime.h>
#include <cstdint>

constexpr int NB   = 8;
constexpr int S    = 1024;
constexpr int CD   = 128;
constexpr int DIN  = 512;
constexpr int BATCH= 16;
constexpr int T    = 4096;
constexpr int NTOK = BATCH * T;        // 65536

// ---------------------------------------------------------------------------
// cbn32[s] = fl32( fp64 sum_d cb[s][d]^2 )
__global__ __launch_bounds__(256) void cbn32_kernel(const float* __restrict__ cbs,
                                                    float* __restrict__ cbn32) {
  int row = blockIdx.x * 256 + threadIdx.x;
  if (row >= NB * S) return;
  const float4* r4 = reinterpret_cast<const float4*>(cbs + (size_t)row * CD);
  double s = 0.0;
  for (int q = 0; q < 32; ++q) {
    float4 v = r4[q];
    s += (double)v.x * v.x + (double)v.y * v.y + (double)v.z * v.z + (double)v.w * v.w;
  }
  cbn32[row] = (float)s;
}

// P64t[k][d] = fp64 sum_D Win[d,D] * Wout[D,k]
__global__ __launch_bounds__(256) void p64t_kernel(const float* __restrict__ Win,
                                                   const float* __restrict__ Wout,
                                                   double* __restrict__ P64t) {
  int n = blockIdx.x * 256 + threadIdx.x;   // 16384
  int k = n >> 7, d = n & 127;
  double s = 0.0;
  for (int D = 0; D < DIN; ++D)
    s = fma((double)Win[(size_t)d * DIN + D], (double)Wout[(size_t)D * CD + k], s);
  P64t[(size_t)k * CD + d] = s;
}

__global__ void cvec64_kernel(const float* __restrict__ Win,
                              const float* __restrict__ bout,
                              double* __restrict__ cvec64) {
  int d = threadIdx.x;  // 128
  double s = 0.0;
  for (int D = 0; D < DIN; ++D)
    s = fma((double)Win[(size_t)d * DIN + D], (double)bout[D], s);
  cvec64[d] = s;
}

// ---------------------------------------------------------------------------
// A64[b][d][t] = fp64( sum_D Win[d,D]*z[b,D,t] + bin[d] )
__global__ __launch_bounds__(256) void a64_kernel(const float* __restrict__ z,
                                                  const float* __restrict__ Win,
                                                  const float* __restrict__ bin,
                                                  double* __restrict__ A64) {
  __shared__ __align__(16) float Al[32][132];
  __shared__ __align__(16) float Bl[32][68];
  const int tid = threadIdx.x;
  const int t0 = blockIdx.x * 64;
  const int b  = blockIdx.y;
  const int mx = tid & 15, nx = tid >> 4;
  double acc[8][4] = {};
  for (int kc = 0; kc < 16; ++kc) {
    __syncthreads();
#pragma unroll
    for (int rep = 0; rep < 4; ++rep) {
      int idx = rep * 256 + tid;
      int r = idx >> 3, q = idx & 7;
      float4 v = reinterpret_cast<const float4*>(Win)[(size_t)r * 128 + kc * 8 + q];
      Al[q * 4 + 0][r] = v.x; Al[q * 4 + 1][r] = v.y;
      Al[q * 4 + 2][r] = v.z; Al[q * 4 + 3][r] = v.w;
    }
#pragma unroll
    for (int rep = 0; rep < 2; ++rep) {
      int idx = rep * 256 + tid;
      int kk = idx >> 4, q = idx & 15;
      float4 v = reinterpret_cast<const float4*>(z + ((size_t)(b * DIN + kc * 32 + kk)) * T + t0)[q];
      *reinterpret_cast<float4*>(&Bl[kk][q * 4]) = v;
    }
    __syncthreads();
#pragma unroll
    for (int kk = 0; kk < 32; ++kk) {
      float4 a0 = *reinterpret_cast<const float4*>(&Al[kk][mx * 8]);
      float4 a1 = *reinterpret_cast<const float4*>(&Al[kk][mx * 8 + 4]);
      float4 bv = *reinterpret_cast<const float4*>(&Bl[kk][nx * 4]);
      double a[8] = {a0.x, a0.y, a0.z, a0.w, a1.x, a1.y, a1.z, a1.w};
      double bb[4] = {bv.x, bv.y, bv.z, bv.w};
#pragma unroll
      for (int u = 0; u < 8; ++u)
#pragma unroll
        for (int j = 0; j < 4; ++j) acc[u][j] = fma(a[u], bb[j], acc[u][j]);
    }
  }
#pragma unroll
  for (int u = 0; u < 8; ++u) {
    int d = mx * 8 + u;
    double bi = (double)bin[d];
    double* Ap = A64 + ((size_t)(b * CD + d)) * T + t0 + nx * 4;
#pragma unroll
    for (int j = 0; j < 4; ++j) Ap[j] = acc[u][j] + bi;
  }
}

// ---------------------------------------------------------------------------
// z32[d][tok] = fl32( A64 - sum_k P64t[k][d]*qs64[k][tok] - book*cvec64[d] )
__global__ __launch_bounds__(256) void zproj32_kernel(const double* __restrict__ A64,
                                                      const double* __restrict__ qs64,
                                                      const double* __restrict__ P64t,
                                                      const double* __restrict__ cvec64,
                                                      float* __restrict__ z32,
                                                      int book) {
  __shared__ double Q[16][64];
  const int tid = threadIdx.x;
  const int tok0 = blockIdx.x * 64;        // flat token tile (never straddles b)
  const int b = tok0 >> 12, tloc = tok0 & (T - 1);
  const int d = tid & 127, h = tid >> 7;
  double acc[32];
  const double* Ap = A64 + ((size_t)(b * CD + d)) * T + tloc + h * 32;
#pragma unroll
  for (int j = 0; j < 32; ++j) acc[j] = Ap[j];
  if (book > 0) {
    for (int kc = 0; kc < 8; ++kc) {
      __syncthreads();
#pragma unroll
      for (int rep = 0; rep < 4; ++rep) {
        int idx = rep * 256 + tid;
        int kkk = idx >> 6, tt = idx & 63;
        Q[kkk][tt] = qs64[(size_t)(kc * 16 + kkk) * NTOK + tok0 + tt];
      }
      __syncthreads();
#pragma unroll
      for (int kk = 0; kk < 16; ++kk) {
        double p = P64t[(size_t)(kc * 16 + kk) * CD + d];
#pragma unroll
        for (int j = 0; j < 32; ++j) acc[j] = fma(-p, Q[kk][h * 32 + j], acc[j]);
      }
    }
    double cv = (double)book * cvec64[d];
#pragma unroll
    for (int j = 0; j < 32; ++j) acc[j] -= cv;
  }
  float* zp = z32 + (size_t)d * NTOK + tok0 + h * 32;
#pragma unroll
  for (int j = 0; j < 32; ++j) zp[j] = (float)acc[j];
}

// ---------------------------------------------------------------------------
// Scores: E64 = fp64 dot(z32[:,t], cb[s,:]); M32 = fl32(E64);
// d2 = fp32( (zn32 - 2f*M32) + cbn32[s] )  — exact fp32 combine, RN, no FMA.
// argmin with first-index ties via ascending strict-< LDS merge.
__global__ __launch_bounds__(256) void score_kernel(const float* __restrict__ z32,
                                                    const float* __restrict__ cb,
                                                    const float* __restrict__ cbn32b,
                                                    int* __restrict__ codes,
                                                    double* __restrict__ lpart,
                                                    int book) {
  __shared__ __align__(16) float Zl[128][68];
  __shared__ __align__(16) float Al[32][132];   // cb staging; aliased by merge arrays
  __shared__ float Cn[128];
  __shared__ double znp[4][64];
  __shared__ float zn[64];
  __shared__ double lred[16];
  const int tid = threadIdx.x;
  const int t0 = blockIdx.x * 64;
  const int b  = blockIdx.y;
  const int mx = tid & 15, nx = tid >> 4;
  const size_t tokbase = (size_t)b * T + t0;

  float* Rm1 = &Al[0][0];                               // 1024 floats
  int*   Ri  = reinterpret_cast<int*>(&Al[0][0]) + 1024; // 1024 ints (Al = 4224 floats)

#pragma unroll
  for (int rep = 0; rep < 8; ++rep) {   // load z32 tile [128][64]
    int idx = rep * 256 + tid;
    int d = idx >> 4, q = idx & 15;
    float4 v = *reinterpret_cast<const float4*>(z32 + (size_t)d * NTOK + tokbase + q * 4);
    *reinterpret_cast<float4*>(&Zl[d][q * 4]) = v;
  }
  __syncthreads();
  { // zn32[t] = fl32( fp64 sum_d z^2 )
    int tt = tid & 63, part = tid >> 6;
    double s = 0.0;
#pragma unroll
    for (int dd = 0; dd < 32; ++dd) { double v = (double)Zl[part * 32 + dd][tt]; s += v * v; }
    znp[part][tt] = s;
  }
  __syncthreads();
  if (tid < 64) zn[tid] = (float)(znp[0][tid] + znp[1][tid] + znp[2][tid] + znp[3][tid]);

  const float INF = 3.4e38f;
  float gm1[4] = {INF, INF, INF, INF};
  int   gi1[4] = {0, 0, 0, 0};

  for (int c = 0; c < 8; ++c) {
    double acc[8][4] = {};
    for (int kc = 0; kc < 4; ++kc) {
      __syncthreads();
      if (kc == 0 && tid < 128) Cn[tid] = cbn32b[c * 128 + tid];
#pragma unroll
      for (int rep = 0; rep < 4; ++rep) {   // stage cb chunk transposed
        int idx = rep * 256 + tid;
        int r = idx >> 3, q = idx & 7;
        float4 v = reinterpret_cast<const float4*>(cb)[(size_t)(c * 128 + r) * 32 + kc * 8 + q];
        Al[q * 4 + 0][r] = v.x; Al[q * 4 + 1][r] = v.y;
        Al[q * 4 + 2][r] = v.z; Al[q * 4 + 3][r] = v.w;
      }
      __syncthreads();
#pragma unroll
      for (int kk = 0; kk < 32; ++kk) {
        float4 a0 = *reinterpret_cast<const float4*>(&Al[kk][mx * 8]);
        float4 a1 = *reinterpret_cast<const float4*>(&Al[kk][mx * 8 + 4]);
        float4 bv = *reinterpret_cast<const float4*>(&Zl[kc * 32 + kk][nx * 4]);
        double a[8] = {a0.x, a0.y, a0.z, a0.w, a1.x, a1.y, a1.z, a1.w};
        double bb[4] = {bv.x, bv.y, bv.z, bv.w};
#pragma unroll
        for (int u = 0; u < 8; ++u)
#pragma unroll
          for (int j = 0; j < 4; ++j) acc[u][j] = fma(a[u], bb[j], acc[u][j]);
      }
    }
    // fp32 combine + per-thread first-index argmin over this chunk's 8 codes
    float tm1[4]; int ti1[4];
#pragma unroll
    for (int j = 0; j < 4; ++j) {
      float m1 = INF; int i1 = 0;
      float znj = zn[nx * 4 + j];
#pragma unroll
      for (int u = 0; u < 8; ++u) {
        float M  = (float)acc[u][j];
        float dv = __fsub_rn(znj, __fmul_rn(2.0f, M));
        float d2 = __fadd_rn(dv, Cn[mx * 8 + u]);
        if (d2 < m1) { m1 = d2; i1 = c * 128 + mx * 8 + u; }
      }
      tm1[j] = m1; ti1[j] = i1;
    }
    __syncthreads();   // Al inner reads done before alias write
#pragma unroll
    for (int j = 0; j < 4; ++j) {
      int slot = j * 256 + nx * 16 + mx;
      Rm1[slot] = tm1[j]; Ri[slot] = ti1[j];
    }
    __syncthreads();
    if (mx == 0) {     // ascending-mx strict-< merge = first-index
#pragma unroll
      for (int j = 0; j < 4; ++j) {
        float m1 = INF; int i1 = 0;
        for (int x = 0; x < 16; ++x) {
          int slot = j * 256 + nx * 16 + x;
          float am = Rm1[slot];
          if (am < m1) { m1 = am; i1 = Ri[slot]; }
        }
        if (m1 < gm1[j]) { gm1[j] = m1; gi1[j] = i1; }   // chunks ascend: keep old on tie
      }
    }
  }
  if (mx == 0) {
    double lp = 0.0;
#pragma unroll
    for (int j = 0; j < 4; ++j) {
      codes[((size_t)b * NB + book) * T + t0 + nx * 4 + j] = gi1[j];
      lp += (double)gm1[j];
    }
    lred[nx] = lp;
  }
  __syncthreads();
  if (tid == 0) {
    double s = 0.0;
#pragma unroll
    for (int i = 0; i < 16; ++i) s += lred[i];
    lpart[(size_t)book * 1024 + b * 64 + blockIdx.x] = s;
  }
}

// ---------------------------------------------------------------------------
__global__ __launch_bounds__(256) void qsum64_kernel(double* __restrict__ qs64,
                                                     const float* __restrict__ cb,
                                                     const int* __restrict__ codes,
                                                     int book) {
  int tok = blockIdx.x * 256 + threadIdx.x;
  int b = tok >> 12, t = tok & (T - 1);
  int code = codes[((size_t)b * NB + book) * T + t];
  const float* row = cb + (size_t)code * CD;
  for (int k = 0; k < CD; ++k)
    qs64[(size_t)k * NTOK + tok] += (double)row[k];
}

// ---------------------------------------------------------------------------
// z_q[b][D][t] = fl32( fp64 sum_k Wout[D][k]*qs64[k][tok] + 8*bout[D] )
__global__ __launch_bounds__(256) void final64_kernel(const double* __restrict__ qs64,
                                                      const float* __restrict__ Wout,
                                                      const float* __restrict__ bout,
                                                      float* __restrict__ out) {
  __shared__ __align__(16) float Al[32][132];
  __shared__ double Bl64[32][65];
  const int tid = threadIdx.x;
  const int t0 = blockIdx.x * 64;
  const int Dg = blockIdx.y;
  const int b  = blockIdx.z;
  const int mx = tid & 15, nx = tid >> 4;
  const size_t tokbase = (size_t)b * T + t0;
  double acc[8][4] = {};
  for (int kc = 0; kc < 4; ++kc) {
    __syncthreads();
#pragma unroll
    for (int rep = 0; rep < 4; ++rep) {
      int idx = rep * 256 + tid;
      int r = idx >> 3, q = idx & 7;
      float4 v = reinterpret_cast<const float4*>(Wout)[(size_t)(Dg * 128 + r) * 32 + kc * 8 + q];
      Al[q * 4 + 0][r] = v.x; Al[q * 4 + 1][r] = v.y;
      Al[q * 4 + 2][r] = v.z; Al[q * 4 + 3][r] = v.w;
    }
#pragma unroll
    for (int rep = 0; rep < 8; ++rep) {
      int idx = rep * 256 + tid;
      int kk = idx >> 6, tt = idx & 63;
      Bl64[kk][tt] = qs64[(size_t)(kc * 32 + kk) * NTOK + tokbase + tt];
    }
    __syncthreads();
#pragma unroll
    for (int kk = 0; kk < 32; ++kk) {
      double a[8];
#pragma unroll
      for (int u = 0; u < 8; ++u) a[u] = (double)Al[kk][mx * 8 + u];
#pragma unroll
      for (int j = 0; j < 4; ++j) {
        double bb = Bl64[kk][nx * 4 + j];
#pragma unroll
        for (int u = 0; u < 8; ++u) acc[u][j] = fma(a[u], bb, acc[u][j]);
      }
    }
  }
#pragma unroll
  for (int u = 0; u < 8; ++u) {
    int D = Dg * 128 + mx * 8 + u;
    double bo = 8.0 * (double)bout[D];
    float4 o = make_float4((float)(acc[u][0] + bo), (float)(acc[u][1] + bo),
                           (float)(acc[u][2] + bo), (float)(acc[u][3] + bo));
    reinterpret_cast<float4*>(out + ((size_t)b * DIN + D) * T + t0)[nx] = o;
  }
}

// ---------------------------------------------------------------------------
__global__ __launch_bounds__(256) void codes_out_kernel(const int* __restrict__ codes,
                                                        float* __restrict__ out) {
  int k = blockIdx.x * 256 + threadIdx.x;
  if (k < BATCH * NB * T)
    out[(size_t)BATCH * DIN * T + k] = (float)codes[k];
}

__global__ __launch_bounds__(256) void loss_out_kernel(const double* __restrict__ lpart,
                                                       float* __restrict__ out) {
  __shared__ double red[256];
  double s = 0.0;
  for (int i = threadIdx.x; i < NB * 1024; i += 256) s += lpart[i];
  red[threadIdx.x] = s;
  __syncthreads();
  for (int off = 128; off; off >>= 1) {
    if (threadIdx.x < off) red[threadIdx.x] += red[threadIdx.x + off];
    __syncthreads();
  }
  if (threadIdx.x == 0)
    out[(size_t)BATCH * DIN * T + (size_t)BATCH * NB * T] =
        (float)(red[0] * 1.25 / 8388608.0);   // (1+BETA)*SSE/(B*T*CD)
}

// ---------------------------------------------------------------------------
extern "C" void kernel_launch(void* const* d_in, const int* in_sizes, int n_in,
                              void* d_out, int out_size, void* d_ws, size_t ws_size,
                              hipStream_t stream) {
  (void)in_sizes; (void)n_in; (void)out_size; (void)ws_size;
  const float* z    = (const float*)d_in[0];
  const float* Win  = (const float*)d_in[1];
  const float* bin  = (const float*)d_in[2];
  const float* Wout = (const float*)d_in[3];
  const float* bout = (const float*)d_in[4];
  const float* cbs  = (const float*)d_in[5];
  float* out = (float*)d_out;

  // A64 (67.1 MB fp64) aliases d_out's z_q region (134 MB); its last reader
  // (zproj32 @ book 7) precedes final64's overwrite on the same stream.
  double* A64 = (double*)d_out;

  char* w = (char*)d_ws;
  double* qs64  = (double*)w;  w += (size_t)CD * NTOK * 8;      // 67.1 MB
  double* P64t  = (double*)w;  w += (size_t)CD * CD * 8;
  double* cvec64= (double*)w;  w += CD * 8;
  double* lpart = (double*)w;  w += (size_t)NB * 1024 * 8;
  float*  z32   = (float*)w;   w += (size_t)CD * NTOK * 4;      // 33.6 MB
  float*  cbn32 = (float*)w;   w += (size_t)NB * S * 4;
  int*    codes = (int*)w;     w += (size_t)BATCH * NB * T * 4; // 2 MB

  cbn32_kernel<<<(NB * S + 255) / 256, 256, 0, stream>>>(cbs, cbn32);
  p64t_kernel<<<64, 256, 0, stream>>>(Win, Wout, P64t);
  cvec64_kernel<<<1, 128, 0, stream>>>(Win, bout, cvec64);
  a64_kernel<<<dim3(T / 64, BATCH), 256, 0, stream>>>(z, Win, bin, A64);
  hipMemsetAsync(qs64, 0, (size_t)CD * NTOK * 8, stream);

  for (int book = 0; book < NB; ++book) {
    const float* cb = cbs + (size_t)book * S * CD;
    zproj32_kernel<<<NTOK / 64, 256, 0, stream>>>(A64, qs64, P64t, cvec64, z32, book);
    score_kernel<<<dim3(T / 64, BATCH), 256, 0, stream>>>(
        z32, cb, cbn32 + book * S, codes, lpart, book);
    qsum64_kernel<<<NTOK / 256, 256, 0, stream>>>(qs64, cb, codes, book);
  }
  final64_kernel<<<dim3(T / 64, DIN / 128, BATCH), 256, 0, stream>>>(qs64, Wout, bout, out);
  codes_out_kernel<<<(BATCH * NB * T + 255) / 256, 256, 0, stream>>>(codes, out);
  loss_out_kernel<<<1, 256, 0, stream>>>(lpart, out);
}